// Round 1
// 500.415 us; speedup vs baseline: 1.0319x; 1.0319x over previous
//
#include <hip/hip_runtime.h>
#include <hip/hip_bf16.h>

#define NE 800000
#define NV 100000
#define NNZN 1600000
#define D 128
#define NB_SCAN 98  // ceil(NV / 1024)

typedef short short8 __attribute__((ext_vector_type(8)));
typedef short s16x4 __attribute__((ext_vector_type(4)));
typedef float f32x4 __attribute__((ext_vector_type(4)));
typedef float f32x2 __attribute__((ext_vector_type(2)));

__device__ __forceinline__ unsigned short f2bfu(float f) {
  union { float f; unsigned u; } x;
  x.f = f;
  unsigned u = x.u;
  u += ((u >> 16) & 1u) + 0x7FFFu;  // round-to-nearest-even
  return (unsigned short)(u >> 16);
}

__device__ __forceinline__ float fsigmoid(float x) {
  return 1.0f / (1.0f + __expf(-x));
}
__device__ __forceinline__ float ftanh(float x) {
  return 2.0f / (1.0f + __expf(-2.0f * x)) - 1.0f;
}

// ---------------- Phase 0: W/bias prep + counts zeroing ----------------
// Zeroing counts here replaces hipMemsetAsync(counts): the runtime's small
// fillBufferAligned path ran at 1.85 GB/s (~232 us for 400 KB) inside the
// timed graph. 131072 threads cover NV=100000; runs before hist_kernel so
// stream ordering guarantees visibility.
__global__ __launch_bounds__(256) void wconv_kernel(
    const float* __restrict__ W_ih, const float* __restrict__ W_hh,
    const float* __restrict__ b_ih, const float* __restrict__ b_hh,
    short* __restrict__ Wcat, float* __restrict__ bcomb,
    int* __restrict__ counts) {
  int idx = blockIdx.x * 256 + threadIdx.x;  // 512*256 = 131072 total
  int n = idx >> 8;
  int k = idx & 255;
  float val = (k < 128) ? W_ih[n * 128 + k] : W_hh[n * 128 + (k - 128)];
  Wcat[idx] = (short)f2bfu(val);
  if (idx < 512) bcomb[idx] = b_ih[idx] + b_hh[idx];
  if (idx < NV) counts[idx] = 0;
}

// ---------------- Phase 1a: histogram of vertex ids ----------------
__global__ __launch_bounds__(256) void hist_kernel(
    const int* __restrict__ vid, int* __restrict__ counts) {
  int j = blockIdx.x * 256 + threadIdx.x;
  if (j < NNZN) atomicAdd(&counts[vid[j]], 1);
}

// ---------------- Phase 1b: exclusive scan (3 kernels) ----------------
__global__ __launch_bounds__(256) void scan1_kernel(
    const int* __restrict__ counts, int* __restrict__ offs, int* __restrict__ bsums) {
  __shared__ int lds[256];
  const int t = threadIdx.x;
  const int base = blockIdx.x * 1024 + t * 4;
  int c[4];
  int s = 0;
#pragma unroll
  for (int i = 0; i < 4; ++i) {
    int idx = base + i;
    c[i] = (idx < NV) ? counts[idx] : 0;
    s += c[i];
  }
  lds[t] = s;
  __syncthreads();
  for (int off = 1; off < 256; off <<= 1) {
    int v = (t >= off) ? lds[t - off] : 0;
    __syncthreads();
    lds[t] += v;
    __syncthreads();
  }
  if (t == 255) bsums[blockIdx.x] = lds[255];
  int run = lds[t] - s;  // exclusive prefix of this thread's 4-group
#pragma unroll
  for (int i = 0; i < 4; ++i) {
    int idx = base + i;
    if (idx < NV) offs[idx] = run;
    run += c[i];
  }
}

__global__ __launch_bounds__(256) void scan2_kernel(int* __restrict__ bsums) {
  __shared__ int lds[256];
  const int t = threadIdx.x;
  int v = (t < NB_SCAN) ? bsums[t] : 0;
  lds[t] = v;
  __syncthreads();
  for (int off = 1; off < 256; off <<= 1) {
    int x = (t >= off) ? lds[t - off] : 0;
    __syncthreads();
    lds[t] += x;
    __syncthreads();
  }
  if (t < NB_SCAN) bsums[t] = lds[t] - v;  // exclusive
}

__global__ __launch_bounds__(256) void scan3_kernel(
    int* __restrict__ offs, const int* __restrict__ bsums) {
  const int base = blockIdx.x * 1024 + threadIdx.x * 4;
  const int add = bsums[blockIdx.x];
#pragma unroll
  for (int i = 0; i < 4; ++i) {
    int idx = base + i;
    if (idx < NV) offs[idx] += add;
  }
}

// ---------------- Phase 1c: scatter edge ids into CSR buckets ----------------
// Atomics directly on offs: after this kernel offs[v] == end-of-bucket.
// gather recovers start = end - counts[v]; the separate cursor array is gone.
__global__ __launch_bounds__(256) void scatter_perm_kernel(
    const int* __restrict__ eid, const int* __restrict__ vid,
    int* __restrict__ offs, int* __restrict__ perm) {
  int j = blockIdx.x * 256 + threadIdx.x;
  if (j < NNZN) {
    int v = vid[j];
    int pos = atomicAdd(&offs[v], 1);
    perm[pos] = eid[j];
  }
}

// ---------------- Phase 2a: gather-sum, one wave per vertex ----------------
// 64 lanes = 2 edge-slots x 32 f32x4 positions. Unroll x4 -> 8 rows (4 KB)
// in flight per wave. Accumulate f32, xor-32 reduce, write msg as bf16.
__global__ __launch_bounds__(256) void gather_kernel(
    const float* __restrict__ x_e, const int* __restrict__ ends,
    const int* __restrict__ counts, const int* __restrict__ perm,
    unsigned short* __restrict__ msg) {
  const int wv = (blockIdx.x * 256 + threadIdx.x) >> 6;  // wave id == vertex id
  const int lane = threadIdx.x & 63;
  const int half = lane >> 5;  // edge parity
  const int pos = lane & 31;   // 16B slot within the 512B row
  if (wv >= NV) return;
  const int deg = counts[wv];
  const int start = ends[wv] - deg;
  f32x4 a0 = {0.f, 0.f, 0.f, 0.f}, a1 = a0, a2 = a0, a3 = a0;
  int i = half;
  for (; i + 6 < deg; i += 8) {
    int e0 = perm[start + i];
    int e1 = perm[start + i + 2];
    int e2 = perm[start + i + 4];
    int e3 = perm[start + i + 6];
    a0 += *(const f32x4*)(x_e + (size_t)e0 * D + pos * 4);
    a1 += *(const f32x4*)(x_e + (size_t)e1 * D + pos * 4);
    a2 += *(const f32x4*)(x_e + (size_t)e2 * D + pos * 4);
    a3 += *(const f32x4*)(x_e + (size_t)e3 * D + pos * 4);
  }
  for (; i < deg; i += 2) {
    int e = perm[start + i];
    a0 += *(const f32x4*)(x_e + (size_t)e * D + pos * 4);
  }
  a0 += a1;
  a2 += a3;
  a0 += a2;
  // combine the two edge-parity halves (lane ^ 32)
  f32x4 b;
  b[0] = __shfl_xor(a0[0], 32);
  b[1] = __shfl_xor(a0[1], 32);
  b[2] = __shfl_xor(a0[2], 32);
  b[3] = __shfl_xor(a0[3], 32);
  a0 += b;
  if (half == 0) {
    s16x4 p;
    p[0] = (short)f2bfu(a0[0]);
    p[1] = (short)f2bfu(a0[1]);
    p[2] = (short)f2bfu(a0[2]);
    p[3] = (short)f2bfu(a0[3]);
    *(s16x4*)(msg + (size_t)wv * D + pos * 4) = p;
  }
}

// ---------------- Phase 2b: GEMM + LSTM cell ----------------
// Block = 256 threads (4 waves), 32 vertices.
// A tile: [32 rows][256 k] bf16 in LDS (XOR-swizzled, row stride 512B).
// Wave w owns feature slice d in [w*32, w*32+32) and computes all 4 gates.
__global__ __launch_bounds__(256) void lstm_kernel(
    const unsigned short* __restrict__ msg, const float* __restrict__ h_v,
    const float* __restrict__ c_v, const short* __restrict__ Wcat,
    const float* __restrict__ bcomb, float* __restrict__ out) {
  __shared__ char Atile[32 * 256 * 2];  // 16 KB
  const int tid = threadIdx.x;
  const int vbase = blockIdx.x * 32;

  // ---- stage A = [msg(bf16) | h_v->bf16] into LDS ----
#pragma unroll
  for (int i = 0; i < 4; ++i) {
    int cid = tid + i * 256;  // 0..1023 = 32 rows x 32 16B-chunks
    int row = cid >> 5;
    int c = cid & 31;
    short8 v;
    if (c < 16) {
      v = *(const short8*)(msg + (size_t)(vbase + row) * D + c * 8);
    } else {
      const float* src = h_v + (size_t)(vbase + row) * D + (c - 16) * 8;
      f32x4 a = *(const f32x4*)(src);
      f32x4 b = *(const f32x4*)(src + 4);
      v[0] = (short)f2bfu(a[0]); v[1] = (short)f2bfu(a[1]);
      v[2] = (short)f2bfu(a[2]); v[3] = (short)f2bfu(a[3]);
      v[4] = (short)f2bfu(b[0]); v[5] = (short)f2bfu(b[1]);
      v[6] = (short)f2bfu(b[2]); v[7] = (short)f2bfu(b[3]);
    }
    int byteoff = row * 512 + c * 16;
    byteoff ^= (row & 7) << 4;  // bank-conflict swizzle
    *(short8*)(Atile + byteoff) = v;
  }
  __syncthreads();

  const int wid = tid >> 6;
  const int lane = tid & 63;
  const int l16 = lane & 15;
  const int lhi = lane >> 4;  // 0..3

  f32x4 acc[2][4][2] = {};  // [m-tile][gate][d-subtile]

#pragma unroll
  for (int kk = 0; kk < 8; ++kk) {
    short8 afrag[2];
#pragma unroll
    for (int m = 0; m < 2; ++m) {
      int row = m * 16 + l16;
      int byteoff = row * 512 + kk * 64 + lhi * 16;
      byteoff ^= (row & 7) << 4;
      afrag[m] = *(const short8*)(Atile + byteoff);
    }
#pragma unroll
    for (int g = 0; g < 4; ++g) {
#pragma unroll
      for (int t = 0; t < 2; ++t) {
        int n0 = g * 128 + wid * 32 + t * 16;
        short8 bfrag = *(const short8*)(Wcat + (size_t)(n0 + l16) * 256 + kk * 32 + lhi * 8);
        acc[0][g][t] = __builtin_amdgcn_mfma_f32_16x16x32_bf16(afrag[0], bfrag, acc[0][g][t], 0, 0, 0);
        acc[1][g][t] = __builtin_amdgcn_mfma_f32_16x16x32_bf16(afrag[1], bfrag, acc[1][g][t], 0, 0, 0);
      }
    }
  }

  // ---- epilogue: activations + cell update, all in-register ----
  float* out_h = out;
  float* out_c = out + (size_t)NV * D;
#pragma unroll
  for (int m = 0; m < 2; ++m) {
#pragma unroll
    for (int t = 0; t < 2; ++t) {
      int d = wid * 32 + t * 16 + l16;
      float bi = bcomb[d];
      float bf = bcomb[128 + d];
      float bg = bcomb[256 + d];
      float bo = bcomb[384 + d];
#pragma unroll
      for (int r = 0; r < 4; ++r) {
        int v = vbase + m * 16 + lhi * 4 + r;
        float gi = acc[m][0][t][r] + bi;
        float gf = acc[m][1][t][r] + bf;
        float gg = acc[m][2][t][r] + bg;
        float go = acc[m][3][t][r] + bo;
        float ii = fsigmoid(gi);
        float ff = fsigmoid(gf);
        float g_ = ftanh(gg);
        float oo = fsigmoid(go);
        float cv = c_v[(size_t)v * D + d];
        float cn = ff * cv + ii * g_;
        float hn = oo * ftanh(cn);
        out_h[(size_t)v * D + d] = hn;
        out_c[(size_t)v * D + d] = cn;
      }
    }
  }
}

extern "C" void kernel_launch(void* const* d_in, const int* in_sizes, int n_in,
                              void* d_out, int out_size, void* d_ws, size_t ws_size,
                              hipStream_t stream) {
  const float* x_e  = (const float*)d_in[0];
  const float* h_v  = (const float*)d_in[1];
  const float* c_v  = (const float*)d_in[2];
  const float* W_ih = (const float*)d_in[3];
  const float* W_hh = (const float*)d_in[4];
  const float* b_ih = (const float*)d_in[5];
  const float* b_hh = (const float*)d_in[6];
  const int* eid    = (const int*)d_in[7];
  const int* vid    = (const int*)d_in[8];
  // d_in[9] = v_batch: unused by the reference computation.
  float* out = (float*)d_out;

  // ws layout: Wcat bf16[512*256] | bcomb f32[512] | counts[NV] | offs[NV] |
  //            bsums[128] | perm[NNZN] | msg bf16[NV*D]
  char* w = (char*)d_ws;
  short* Wcat  = (short*)w;                 w += 512 * 256 * sizeof(short);
  float* bcomb = (float*)w;                 w += 512 * sizeof(float);
  int* counts  = (int*)w;                   w += NV * sizeof(int);
  int* offs    = (int*)w;                   w += NV * sizeof(int);
  int* bsums   = (int*)w;                   w += 128 * sizeof(int);
  int* perm    = (int*)w;                   w += NNZN * sizeof(int);
  unsigned short* msg = (unsigned short*)w;

  wconv_kernel<<<512, 256, 0, stream>>>(W_ih, W_hh, b_ih, b_hh, Wcat, bcomb, counts);
  hist_kernel<<<(NNZN + 255) / 256, 256, 0, stream>>>(vid, counts);
  scan1_kernel<<<NB_SCAN, 256, 0, stream>>>(counts, offs, bsums);
  scan2_kernel<<<1, 256, 0, stream>>>(bsums);
  scan3_kernel<<<NB_SCAN, 256, 0, stream>>>(offs, bsums);
  scatter_perm_kernel<<<(NNZN + 255) / 256, 256, 0, stream>>>(eid, vid, offs, perm);
  gather_kernel<<<(NV + 3) / 4, 256, 0, stream>>>(x_e, offs, counts, perm, msg);
  lstm_kernel<<<NV / 32, 256, 0, stream>>>(msg, h_v, c_v, Wcat, bcomb, out);
}